// Round 13
// baseline (363.598 us; speedup 1.0000x reference)
//
#include <hip/hip_runtime.h>
#include <hip/hip_bf16.h>

#define N_NODES 20000
#define N_EDGES 180000
#define D_OUT   768
#define D_H1    128
#define B_SZ    16
#define S_LEN   512
#define NEG_SLOPE_C 0.2f

typedef __attribute__((ext_vector_type(8))) short bf16x8;   // 8 bf16 = 4 VGPRs
typedef __attribute__((ext_vector_type(4))) float f32x4;    // MFMA acc

__device__ __forceinline__ float leaky1(float x){ return x >= 0.0f ? x : NEG_SLOPE_C * x; }
__device__ __forceinline__ unsigned short f2bf(float x){
  union { __hip_bfloat16 h; unsigned short u; } v; v.h = __float2bfloat16(x); return v.u;
}
__device__ __forceinline__ float bf2f(unsigned short u){
  return __uint_as_float(((unsigned)u) << 16);
}
__device__ __forceinline__ float4 bf4_to_f4(ushort4 u){
  return make_float4(bf2f(u.x), bf2f(u.y), bf2f(u.z), bf2f(u.w));
}
__device__ __forceinline__ ushort4 f4_to_bf4(float4 v){
  ushort4 u; u.x=f2bf(v.x); u.y=f2bf(v.y); u.z=f2bf(v.z); u.w=f2bf(v.w); return u;
}

// 12-element leaky-dot for layer-2 scores
__device__ __forceinline__ float score12(const float4&u0,const float4&u1,const float4&u2,
                                         const float4&h0,const float4&h1,const float4&h2v,
                                         const float4&a0,const float4&a1,const float4&a2){
  return leaky1(u0.x+h0.x)*a0.x + leaky1(u0.y+h0.y)*a0.y
       + leaky1(u0.z+h0.z)*a0.z + leaky1(u0.w+h0.w)*a0.w
       + leaky1(u1.x+h1.x)*a1.x + leaky1(u1.y+h1.y)*a1.y
       + leaky1(u1.z+h1.z)*a1.z + leaky1(u1.w+h1.w)*a1.w
       + leaky1(u2.x+h2v.x)*a2.x + leaky1(u2.y+h2v.y)*a2.y
       + leaky1(u2.z+h2v.z)*a2.z + leaky1(u2.w+h2v.w)*a2.w;
}
__device__ __forceinline__ void rescale_if(float mn, float&m, float&den,
                                           float4&a0,float4&a1,float4&a2){
  if(mn > m){                               // wave-uniform (scores reduced over wave)
    float r = expf(m - mn);                 // first time: expf(-inf)=0
    den *= r;
    a0.x*=r; a0.y*=r; a0.z*=r; a0.w*=r;
    a1.x*=r; a1.y*=r; a1.z*=r; a1.w*=r;
    a2.x*=r; a2.y*=r; a2.z*=r; a2.w*=r;
    m = mn;
  }
}
__device__ __forceinline__ void axpy12(float w, const float4&u0,const float4&u1,const float4&u2,
                                       float4&a0,float4&a1,float4&a2){
  a0.x+=w*u0.x; a0.y+=w*u0.y; a0.z+=w*u0.z; a0.w+=w*u0.w;
  a1.x+=w*u1.x; a1.y+=w*u1.y; a1.z+=w*u1.z; a1.w+=w*u1.w;
  a2.x+=w*u2.x; a2.y+=w*u2.y; a2.z+=w*u2.z; a2.w+=w*u2.w;
}
// drain helpers (one node): two edges / one edge
__device__ __forceinline__ void edge_pair(const unsigned short* __restrict__ hs2,
    const int* __restrict__ es, const int* __restrict__ eidx, int k, int l,
    const float4&h0,const float4&h1,const float4&h2v,
    const float4&w0,const float4&w1,const float4&w2,
    float&m,float&den,float4&a0,float4&a1,float4&a2){
  int e0=eidx[k], e1=eidx[k+1];
  const ushort4* p0=(const ushort4*)(hs2+(size_t)es[e0]*D_OUT);
  const ushort4* p1=(const ushort4*)(hs2+(size_t)es[e1]*D_OUT);
  float4 u0=bf4_to_f4(p0[l]),u1=bf4_to_f4(p0[64+l]),u2=bf4_to_f4(p0[128+l]);
  float4 v0=bf4_to_f4(p1[l]),v1=bf4_to_f4(p1[64+l]),v2=bf4_to_f4(p1[128+l]);
  float s0=score12(u0,u1,u2,h0,h1,h2v,w0,w1,w2);
  float s1=score12(v0,v1,v2,h0,h1,h2v,w0,w1,w2);
  #pragma unroll
  for(int off=1; off<64; off<<=1){ s0+=__shfl_xor(s0,off,64); s1+=__shfl_xor(s1,off,64); }
  float mn=fmaxf(m,fmaxf(s0,s1));
  rescale_if(mn,m,den,a0,a1,a2);
  float q0=expf(s0-m), q1=expf(s1-m);
  den+=q0+q1;
  axpy12(q0,u0,u1,u2,a0,a1,a2);
  axpy12(q1,v0,v1,v2,a0,a1,a2);
}
__device__ __forceinline__ void edge_one(const unsigned short* __restrict__ hs2,
    const int* __restrict__ es, const int* __restrict__ eidx, int k, int l,
    const float4&h0,const float4&h1,const float4&h2v,
    const float4&w0,const float4&w1,const float4&w2,
    float&m,float&den,float4&a0,float4&a1,float4&a2){
  int e0=eidx[k];
  const ushort4* p0=(const ushort4*)(hs2+(size_t)es[e0]*D_OUT);
  float4 u0=bf4_to_f4(p0[l]),u1=bf4_to_f4(p0[64+l]),u2=bf4_to_f4(p0[128+l]);
  float s0=score12(u0,u1,u2,h0,h1,h2v,w0,w1,w2);
  #pragma unroll
  for(int off=1; off<64; off<<=1) s0+=__shfl_xor(s0,off,64);
  float mn=fmaxf(m,s0);
  rescale_if(mn,m,den,a0,a1,a2);
  float q0=expf(s0-m);
  den+=q0;
  axpy12(q0,u0,u1,u2,a0,a1,a2);
}

// ---------------- CSR build (by destination) ----------------
__global__ void k_count(const int* __restrict__ ed, int* __restrict__ deg){
  int e = blockIdx.x*256 + threadIdx.x;
  if(e < N_EDGES) atomicAdd(&deg[ed[e]], 1);
}

__global__ void k_scan(const int* __restrict__ deg, int* __restrict__ row_ptr, int* __restrict__ cursor){
  __shared__ int part[256];
  int t = threadIdx.x;
  const int CH = (N_NODES + 255) / 256;
  int base = t * CH;
  int s = 0;
  for(int i=0;i<CH;i++){ int n = base+i; if(n < N_NODES) s += deg[n]; }
  part[t] = s;
  __syncthreads();
  for(int off=1; off<256; off<<=1){
    int v = (t >= off) ? part[t-off] : 0;
    __syncthreads();
    part[t] += v;
    __syncthreads();
  }
  int run = (t==0) ? 0 : part[t-1];
  for(int i=0;i<CH;i++){
    int n = base+i;
    if(n < N_NODES){ row_ptr[n] = run; cursor[n] = run; run += deg[n]; }
  }
  if(t == 255) row_ptr[N_NODES] = run;
}

__global__ void k_scatter(const int* __restrict__ ed, int* __restrict__ cursor, int* __restrict__ eidx){
  int e = blockIdx.x*256 + threadIdx.x;
  if(e < N_EDGES){
    int pos = atomicAdd(&cursor[ed[e]], 1);
    eidx[pos] = e;
  }
}

// ---------------- Layer 1: node transforms (K=4), bf16 outputs ----------------
__global__ void k_gemm1(const float* __restrict__ feat, const float* __restrict__ Ws,
                        const float* __restrict__ Wd,
                        unsigned short* __restrict__ hs1, unsigned short* __restrict__ hd1){
  int idx = blockIdx.x*256 + threadIdx.x;
  if(idx >= N_NODES*D_H1) return;
  int n = idx >> 7, hf = idx & 127;
  float f0 = feat[n*4+0], f1 = feat[n*4+1], f2 = feat[n*4+2], f3 = feat[n*4+3];
  hs1[idx] = f2bf(f0*Ws[hf] + f1*Ws[128+hf] + f2*Ws[256+hf] + f3*Ws[384+hf]);
  hd1[idx] = f2bf(f0*Wd[hf] + f1*Wd[128+hf] + f2*Wd[256+hf] + f3*Wd[384+hf]);
}

// ---------------- Layer 1 fused (unroll-2): scores + online softmax + aggregate + ELU ----------------
__global__ void k_fused1(const unsigned short* __restrict__ hs1, const unsigned short* __restrict__ hd1,
                         const int* __restrict__ es, const int* __restrict__ row_ptr,
                         const int* __restrict__ eidx, const float* __restrict__ attn1,
                         unsigned short* __restrict__ h1){
  int node = blockIdx.x*4 + (threadIdx.x >> 6);
  int l = threadIdx.x & 63;
  if(node >= N_NODES) return;
  int rp = row_ptr[node], re = row_ptr[node+1];
  float hda = bf2f(hd1[(size_t)node*D_H1 + l]);
  float hdb = bf2f(hd1[(size_t)node*D_H1 + 64 + l]);
  float awa = attn1[l], awb = attn1[64 + l];
  float m0 = -INFINITY, m1 = -INFINITY;
  float d0 = 0.f, d1 = 0.f, a0 = 0.f, a1 = 0.f;
  int k = rp;
  for(; k+1 < re; k += 2){
    int e0 = eidx[k], e1 = eidx[k+1];
    int s0 = es[e0],  s1 = es[e1];
    float xa0 = bf2f(hs1[(size_t)s0*D_H1 + l]);
    float xb0 = bf2f(hs1[(size_t)s0*D_H1 + 64 + l]);
    float xa1 = bf2f(hs1[(size_t)s1*D_H1 + l]);
    float xb1 = bf2f(hs1[(size_t)s1*D_H1 + 64 + l]);
    float ta0 = leaky1(xa0 + hda) * awa;
    float tb0 = leaky1(xb0 + hdb) * awb;
    float ta1 = leaky1(xa1 + hda) * awa;
    float tb1 = leaky1(xb1 + hdb) * awb;
    #pragma unroll
    for(int off=1; off<16; off<<=1){
      ta0 += __shfl_xor(ta0, off, 64);
      tb0 += __shfl_xor(tb0, off, 64);
      ta1 += __shfl_xor(ta1, off, 64);
      tb1 += __shfl_xor(tb1, off, 64);
    }
    float mn0 = fmaxf(m0, fmaxf(ta0, ta1));
    float mn1 = fmaxf(m1, fmaxf(tb0, tb1));
    float r0 = expf(m0 - mn0), r1 = expf(m1 - mn1);
    float wa0 = expf(ta0 - mn0), wa1 = expf(ta1 - mn0);
    float wb0 = expf(tb0 - mn1), wb1 = expf(tb1 - mn1);
    d0 = d0*r0 + wa0 + wa1;
    d1 = d1*r1 + wb0 + wb1;
    a0 = a0*r0 + wa0*xa0 + wa1*xa1;
    a1 = a1*r1 + wb0*xb0 + wb1*xb1;
    m0 = mn0; m1 = mn1;
  }
  if(k < re){
    int e = eidx[k]; int s = es[e];
    float xa = bf2f(hs1[(size_t)s*D_H1 + l]);
    float xb = bf2f(hs1[(size_t)s*D_H1 + 64 + l]);
    float t0 = leaky1(xa + hda) * awa;
    float t1 = leaky1(xb + hdb) * awb;
    #pragma unroll
    for(int off=1; off<16; off<<=1){
      t0 += __shfl_xor(t0, off, 64);
      t1 += __shfl_xor(t1, off, 64);
    }
    float mn0 = fmaxf(m0, t0), mn1 = fmaxf(m1, t1);
    float r0 = expf(m0 - mn0), r1 = expf(m1 - mn1);
    float w0 = expf(t0 - mn0), w1 = expf(t1 - mn1);
    d0 = d0*r0 + w0;      d1 = d1*r1 + w1;
    a0 = a0*r0 + w0*xa;   a1 = a1*r1 + w1*xb;
    m0 = mn0; m1 = mn1;
  }
  float v0 = a0 / d0, v1 = a1 / d1;
  v0 = v0 > 0.f ? v0 : expm1f(v0);
  v1 = v1 > 0.f ? v1 : expm1f(v1);
  h1[(size_t)node*D_H1 + l]      = f2bf(v0);
  h1[(size_t)node*D_H1 + 64 + l] = f2bf(v1);
}

// ---------------- W2 prep: fp32 [k][768] -> bf16 transposed [col][k] ----------------
__global__ void k_wprep(const float* __restrict__ Ws, const float* __restrict__ Wd,
                        unsigned short* __restrict__ WtS, unsigned short* __restrict__ WtD){
  int i = blockIdx.x*256 + threadIdx.x;   // over 768*128
  if(i >= D_OUT*D_H1) return;
  int c = i >> 7, k = i & 127;
  WtS[i] = f2bf(Ws[(size_t)k*D_OUT + c]);
  WtD[i] = f2bf(Wd[(size_t)k*D_OUT + c]);
}

// ---------------- Layer 2: MFMA bf16 GEMM (20000x128)@(128x768), both mats ----------------
__global__ __launch_bounds__(256) void k_gemm2m(const unsigned short* __restrict__ h1b,
                        const unsigned short* __restrict__ WtS, const unsigned short* __restrict__ WtD,
                        unsigned short* __restrict__ hs2, unsigned short* __restrict__ hd2){
  int wave = threadIdx.x >> 6, lane = threadIdx.x & 63;
  int wr = wave >> 1, wc = wave & 1;
  int m0 = blockIdx.x*64 + wr*32;
  int c0 = blockIdx.y*128 + wc*64;
  int lr = lane & 15, lk = lane >> 4;

  f32x4 acc[2][4][2];
  #pragma unroll
  for(int a=0;a<2;a++)
    #pragma unroll
    for(int j=0;j<4;j++)
      #pragma unroll
      for(int mmat=0;mmat<2;mmat++)
        acc[a][j][mmat] = (f32x4){0.f,0.f,0.f,0.f};

  int ra0 = m0 + lr;      if(ra0 > N_NODES-1) ra0 = N_NODES-1;
  int ra1 = m0 + 16 + lr; if(ra1 > N_NODES-1) ra1 = N_NODES-1;
  const unsigned short* pa0 = h1b + (size_t)ra0*D_H1 + lk*8;
  const unsigned short* pa1 = h1b + (size_t)ra1*D_H1 + lk*8;

  #pragma unroll
  for(int t=0;t<4;t++){              // K = 4 x 32
    bf16x8 a0 = *(const bf16x8*)(pa0 + t*32);
    bf16x8 a1 = *(const bf16x8*)(pa1 + t*32);
    #pragma unroll
    for(int j=0;j<4;j++){
      size_t bo = (size_t)(c0 + j*16 + lr)*D_H1 + t*32 + lk*8;
      bf16x8 bs = *(const bf16x8*)(WtS + bo);
      bf16x8 bd = *(const bf16x8*)(WtD + bo);
      acc[0][j][0] = __builtin_amdgcn_mfma_f32_16x16x32_bf16(a0, bs, acc[0][j][0], 0, 0, 0);
      acc[1][j][0] = __builtin_amdgcn_mfma_f32_16x16x32_bf16(a1, bs, acc[1][j][0], 0, 0, 0);
      acc[0][j][1] = __builtin_amdgcn_mfma_f32_16x16x32_bf16(a0, bd, acc[0][j][1], 0, 0, 0);
      acc[1][j][1] = __builtin_amdgcn_mfma_f32_16x16x32_bf16(a1, bd, acc[1][j][1], 0, 0, 0);
    }
  }

  #pragma unroll
  for(int a=0;a<2;a++){
    #pragma unroll
    for(int r=0;r<4;r++){
      int row = m0 + a*16 + lk*4 + r;
      if(row < N_NODES){
        size_t base = (size_t)row*D_OUT;
        #pragma unroll
        for(int j=0;j<4;j++){
          int col = c0 + j*16 + lr;
          hs2[base + col] = f2bf(acc[a][j][0][r]);
          hd2[base + col] = f2bf(acc[a][j][1][r]);
        }
      }
    }
  }
}

// ---------------- Layer 2 fused v3: 2 nodes/wave x unroll-2 (4 gathers in flight) ----------------
// h2 output is bf16 now.
__global__ __launch_bounds__(256) void k_fused2(const unsigned short* __restrict__ hs2,
                         const unsigned short* __restrict__ hd2,
                         const int* __restrict__ es, const int* __restrict__ row_ptr,
                         const int* __restrict__ eidx, const float* __restrict__ attn2,
                         unsigned short* __restrict__ h2){
  int wv = threadIdx.x >> 6, l = threadIdx.x & 63;
  int nA = blockIdx.x*8 + wv*2;          // N_NODES = 20000 = 2500 blocks * 8
  int nB = nA + 1;
  if(nA >= N_NODES) return;
  bool hasB = (nB < N_NODES);

  const float4* pa = (const float4*)attn2;
  float4 aw0 = pa[l], aw1 = pa[64+l], aw2 = pa[128+l];
  const ushort4* pdA = (const ushort4*)(hd2 + (size_t)nA*D_OUT);
  float4 hA0 = bf4_to_f4(pdA[l]), hA1 = bf4_to_f4(pdA[64+l]), hA2 = bf4_to_f4(pdA[128+l]);
  float4 hB0, hB1, hB2;
  if(hasB){
    const ushort4* pdB = (const ushort4*)(hd2 + (size_t)nB*D_OUT);
    hB0 = bf4_to_f4(pdB[l]); hB1 = bf4_to_f4(pdB[64+l]); hB2 = bf4_to_f4(pdB[128+l]);
  } else { hB0 = hB1 = hB2 = make_float4(0,0,0,0); }

  int kA = row_ptr[nA], reA = row_ptr[nA+1];
  int kB = hasB ? row_ptr[nB] : 0, reB = hasB ? row_ptr[nB+1] : 0;

  float mA = -INFINITY, dA = 0.f;
  float mB = -INFINITY, dB = 0.f;
  float4 aA0 = make_float4(0,0,0,0), aA1 = aA0, aA2 = aA0;
  float4 aB0 = aA0, aB1 = aA0, aB2 = aA0;

  // joint loop: 4 rows in flight (pair for A, pair for B)
  while(kA+1 < reA && kB+1 < reB){
    int eA0 = eidx[kA], eA1 = eidx[kA+1], eB0 = eidx[kB], eB1 = eidx[kB+1];
    const ushort4* p0 = (const ushort4*)(hs2 + (size_t)es[eA0]*D_OUT);
    const ushort4* p1 = (const ushort4*)(hs2 + (size_t)es[eA1]*D_OUT);
    const ushort4* p2 = (const ushort4*)(hs2 + (size_t)es[eB0]*D_OUT);
    const ushort4* p3 = (const ushort4*)(hs2 + (size_t)es[eB1]*D_OUT);
    float4 uA0=bf4_to_f4(p0[l]), uA1=bf4_to_f4(p0[64+l]), uA2=bf4_to_f4(p0[128+l]);
    float4 vA0=bf4_to_f4(p1[l]), vA1=bf4_to_f4(p1[64+l]), vA2=bf4_to_f4(p1[128+l]);
    float4 uB0=bf4_to_f4(p2[l]), uB1=bf4_to_f4(p2[64+l]), uB2=bf4_to_f4(p2[128+l]);
    float4 vB0=bf4_to_f4(p3[l]), vB1=bf4_to_f4(p3[64+l]), vB2=bf4_to_f4(p3[128+l]);
    float s0 = score12(uA0,uA1,uA2, hA0,hA1,hA2, aw0,aw1,aw2);
    float s1 = score12(vA0,vA1,vA2, hA0,hA1,hA2, aw0,aw1,aw2);
    float s2 = score12(uB0,uB1,uB2, hB0,hB1,hB2, aw0,aw1,aw2);
    float s3 = score12(vB0,vB1,vB2, hB0,hB1,hB2, aw0,aw1,aw2);
    #pragma unroll
    for(int off=1; off<64; off<<=1){
      s0 += __shfl_xor(s0, off, 64);
      s1 += __shfl_xor(s1, off, 64);
      s2 += __shfl_xor(s2, off, 64);
      s3 += __shfl_xor(s3, off, 64);
    }
    float mnA = fmaxf(mA, fmaxf(s0, s1));
    rescale_if(mnA, mA, dA, aA0, aA1, aA2);
    float qa0 = expf(s0 - mA), qa1 = expf(s1 - mA);
    dA += qa0 + qa1;
    axpy12(qa0, uA0,uA1,uA2, aA0,aA1,aA2);
    axpy12(qa1, vA0,vA1,vA2, aA0,aA1,aA2);
    float mnB = fmaxf(mB, fmaxf(s2, s3));
    rescale_if(mnB, mB, dB, aB0, aB1, aB2);
    float qb0 = expf(s2 - mB), qb1 = expf(s3 - mB);
    dB += qb0 + qb1;
    axpy12(qb0, uB0,uB1,uB2, aB0,aB1,aB2);
    axpy12(qb1, vB0,vB1,vB2, aB0,aB1,aB2);
    kA += 2; kB += 2;
  }
  // drains
  while(kA+1 < reA){ edge_pair(hs2, es, eidx, kA, l, hA0,hA1,hA2, aw0,aw1,aw2, mA,dA,aA0,aA1,aA2); kA += 2; }
  while(kB+1 < reB){ edge_pair(hs2, es, eidx, kB, l, hB0,hB1,hB2, aw0,aw1,aw2, mB,dB,aB0,aB1,aB2); kB += 2; }
  if(kA < reA) edge_one(hs2, es, eidx, kA, l, hA0,hA1,hA2, aw0,aw1,aw2, mA,dA,aA0,aA1,aA2);
  if(kB < reB) edge_one(hs2, es, eidx, kB, l, hB0,hB1,hB2, aw0,aw1,aw2, mB,dB,aB0,aB1,aB2);

  {
    float rd = 1.f/dA;
    ushort4* po = (ushort4*)(h2 + (size_t)nA*D_OUT);
    aA0.x*=rd; aA0.y*=rd; aA0.z*=rd; aA0.w*=rd;
    aA1.x*=rd; aA1.y*=rd; aA1.z*=rd; aA1.w*=rd;
    aA2.x*=rd; aA2.y*=rd; aA2.z*=rd; aA2.w*=rd;
    po[l] = f4_to_bf4(aA0); po[64+l] = f4_to_bf4(aA1); po[128+l] = f4_to_bf4(aA2);
  }
  if(hasB){
    float rd = 1.f/dB;
    ushort4* po = (ushort4*)(h2 + (size_t)nB*D_OUT);
    aB0.x*=rd; aB0.y*=rd; aB0.z*=rd; aB0.w*=rd;
    aB1.x*=rd; aB1.y*=rd; aB1.z*=rd; aB1.w*=rd;
    aB2.x*=rd; aB2.y*=rd; aB2.z*=rd; aB2.w*=rd;
    po[l] = f4_to_bf4(aB0); po[64+l] = f4_to_bf4(aB1); po[128+l] = f4_to_bf4(aB2);
  }
}

// ---------------- Output assembly (h2 is bf16 now) ----------------
__global__ __launch_bounds__(192) void k_out(const unsigned short* __restrict__ h2,
    const int* __restrict__ tok, const int* __restrict__ mins, const int* __restrict__ wkd,
    const int* __restrict__ dayl, const int* __restrict__ grd,
    const float* __restrict__ grid_t, const float* __restrict__ dayt_t,
    const float* __restrict__ week_t, const float* __restrict__ day_t,
    float* __restrict__ out){
  int bs = blockIdx.x;
  int t  = threadIdx.x;
  int s  = bs & (S_LEN-1);
  int tk = tok[bs], mn = mins[bs], wk = wkd[bs], dy = dayl[bs], gr = grd[bs];
  float4 r = bf4_to_f4(((const ushort4*)(h2 + (size_t)tk*D_OUT))[t]);
  float4 v;
  v = ((const float4*)(week_t + (size_t)wk*D_OUT))[t]; r.x+=v.x; r.y+=v.y; r.z+=v.z; r.w+=v.w;
  v = ((const float4*)(dayt_t + (size_t)mn*D_OUT))[t]; r.x+=v.x; r.y+=v.y; r.z+=v.z; r.w+=v.w;
  v = ((const float4*)(day_t  + (size_t)dy*D_OUT))[t]; r.x+=v.x; r.y+=v.y; r.z+=v.z; r.w+=v.w;
  v = ((const float4*)(grid_t + (size_t)gr*D_OUT))[t]; r.x+=v.x; r.y+=v.y; r.z+=v.z; r.w+=v.w;
  const float K = 0.011992630692677313f;   // ln(10000)/768
  float d0 = expf(-K * (float)(4*t));
  float d1 = expf(-K * (float)(4*t+2));
  float sf = (float)s;
  r.x += sinf(sf*d0); r.y += cosf(sf*d0);
  r.z += sinf(sf*d1); r.w += cosf(sf*d1);
  ((float4*)(out + (size_t)bs*D_OUT))[t] = r;
}

extern "C" void kernel_launch(void* const* d_in, const int* in_sizes, int n_in,
                              void* d_out, int out_size, void* d_ws, size_t ws_size,
                              hipStream_t stream) {
  const int*   trj   = (const int*)  d_in[0];
  const int*   mins  = (const int*)  d_in[1];
  const int*   wkd   = (const int*)  d_in[2];
  const int*   dayl  = (const int*)  d_in[3];
  const int*   grd   = (const int*)  d_in[4];
  const int*   es    = (const int*)  d_in[6];
  const int*   ed    = (const int*)  d_in[7];
  const float* feat  = (const float*)d_in[8];
  const float* Ws1   = (const float*)d_in[9];
  const float* Wd1   = (const float*)d_in[10];
  const float* attn1 = (const float*)d_in[11];
  const float* Ws2   = (const float*)d_in[12];
  const float* Wd2   = (const float*)d_in[13];
  const float* attn2 = (const float*)d_in[14];
  const float* gridt = (const float*)d_in[15];
  const float* daytt = (const float*)d_in[16];
  const float* weekt = (const float*)d_in[17];
  const float* dayt  = (const float*)d_in[18];
  float* out = (float*)d_out;

  char* ws = (char*)d_ws;
  size_t off = 0;
  auto alloc = [&](size_t bytes)->char*{
    char* p = ws + off;
    off += bytes;
    off = (off + 255) & ~(size_t)255;
    return p;
  };
  unsigned short* hs1 = (unsigned short*)alloc((size_t)N_NODES*D_H1*2);
  unsigned short* hd1 = (unsigned short*)alloc((size_t)N_NODES*D_H1*2);
  unsigned short* h1  = (unsigned short*)alloc((size_t)N_NODES*D_H1*2);
  unsigned short* WtS = (unsigned short*)alloc((size_t)D_OUT*D_H1*2);
  unsigned short* WtD = (unsigned short*)alloc((size_t)D_OUT*D_H1*2);
  unsigned short* hs2 = (unsigned short*)alloc((size_t)N_NODES*D_OUT*2);
  unsigned short* hd2 = (unsigned short*)alloc((size_t)N_NODES*D_OUT*2);
  unsigned short* h2  = (unsigned short*)alloc((size_t)N_NODES*D_OUT*2);
  int* deg      = (int*)alloc((size_t)N_NODES*4);
  int* row_ptr  = (int*)alloc((size_t)(N_NODES+1)*4);
  int* cursor   = (int*)alloc((size_t)N_NODES*4);
  int* eidx     = (int*)alloc((size_t)N_EDGES*4);

  // CSR by destination (ws re-poisoned each run -> must zero deg)
  hipMemsetAsync(deg, 0, (size_t)N_NODES*4, stream);
  k_count  <<<(N_EDGES+255)/256, 256, 0, stream>>>(ed, deg);
  k_scan   <<<1, 256, 0, stream>>>(deg, row_ptr, cursor);
  k_scatter<<<(N_EDGES+255)/256, 256, 0, stream>>>(ed, cursor, eidx);

  // Layer 1
  k_gemm1 <<<(N_NODES*D_H1)/256, 256, 0, stream>>>(feat, Ws1, Wd1, hs1, hd1);
  k_fused1<<<(N_NODES+3)/4, 256, 0, stream>>>(hs1, hd1, es, row_ptr, eidx, attn1, h1);

  // Layer 2 (MFMA)
  k_wprep <<<(D_OUT*D_H1+255)/256, 256, 0, stream>>>(Ws2, Wd2, WtS, WtD);
  dim3 g2((N_NODES+63)/64, D_OUT/128);
  k_gemm2m<<<g2, 256, 0, stream>>>(h1, WtS, WtD, hs2, hd2);
  k_fused2<<<(N_NODES+7)/8, 256, 0, stream>>>(hs2, hd2, es, row_ptr, eidx, attn2, h2);

  // Output
  k_out<<<B_SZ*S_LEN, 192, 0, stream>>>(h2, trj, mins, wkd, dayl, grd,
                                        gridt, daytt, weekt, dayt, out);
}

// Round 14
// 339.206 us; speedup vs baseline: 1.0719x; 1.0719x over previous
//
#include <hip/hip_runtime.h>
#include <hip/hip_bf16.h>

#define N_NODES 20000
#define N_EDGES 180000
#define D_OUT   768
#define D_H1    128
#define B_SZ    16
#define S_LEN   512
#define NEG_SLOPE_C 0.2f

typedef __attribute__((ext_vector_type(8))) short bf16x8;   // 8 bf16 = 4 VGPRs
typedef __attribute__((ext_vector_type(4))) float f32x4;    // MFMA acc

__device__ __forceinline__ float leaky1(float x){ return x >= 0.0f ? x : NEG_SLOPE_C * x; }
__device__ __forceinline__ unsigned short f2bf(float x){
  union { __hip_bfloat16 h; unsigned short u; } v; v.h = __float2bfloat16(x); return v.u;
}
__device__ __forceinline__ float bf2f(unsigned short u){
  return __uint_as_float(((unsigned)u) << 16);
}
__device__ __forceinline__ float4 bf4_to_f4(ushort4 u){
  return make_float4(bf2f(u.x), bf2f(u.y), bf2f(u.z), bf2f(u.w));
}
__device__ __forceinline__ ushort4 f4_to_bf4(float4 v){
  ushort4 u; u.x=f2bf(v.x); u.y=f2bf(v.y); u.z=f2bf(v.z); u.w=f2bf(v.w); return u;
}

// 12-element leaky-dot for layer-2 scores
__device__ __forceinline__ float score12(const float4&u0,const float4&u1,const float4&u2,
                                         const float4&h0,const float4&h1,const float4&h2v,
                                         const float4&a0,const float4&a1,const float4&a2){
  return leaky1(u0.x+h0.x)*a0.x + leaky1(u0.y+h0.y)*a0.y
       + leaky1(u0.z+h0.z)*a0.z + leaky1(u0.w+h0.w)*a0.w
       + leaky1(u1.x+h1.x)*a1.x + leaky1(u1.y+h1.y)*a1.y
       + leaky1(u1.z+h1.z)*a1.z + leaky1(u1.w+h1.w)*a1.w
       + leaky1(u2.x+h2v.x)*a2.x + leaky1(u2.y+h2v.y)*a2.y
       + leaky1(u2.z+h2v.z)*a2.z + leaky1(u2.w+h2v.w)*a2.w;
}
__device__ __forceinline__ void rescale_if(float mn, float&m, float&den,
                                           float4&a0,float4&a1,float4&a2){
  if(mn > m){                               // wave-uniform (scores reduced over wave)
    float r = expf(m - mn);                 // first time: expf(-inf)=0
    den *= r;
    a0.x*=r; a0.y*=r; a0.z*=r; a0.w*=r;
    a1.x*=r; a1.y*=r; a1.z*=r; a1.w*=r;
    a2.x*=r; a2.y*=r; a2.z*=r; a2.w*=r;
    m = mn;
  }
}
__device__ __forceinline__ void axpy12(float w, const float4&u0,const float4&u1,const float4&u2,
                                       float4&a0,float4&a1,float4&a2){
  a0.x+=w*u0.x; a0.y+=w*u0.y; a0.z+=w*u0.z; a0.w+=w*u0.w;
  a1.x+=w*u1.x; a1.y+=w*u1.y; a1.z+=w*u1.z; a1.w+=w*u1.w;
  a2.x+=w*u2.x; a2.y+=w*u2.y; a2.z+=w*u2.z; a2.w+=w*u2.w;
}
// fused2 bodies: src ids passed directly (no index loads inside)
__device__ __forceinline__ void f2_pair(const unsigned short* __restrict__ hs2,
    int s0i, int s1i, int l,
    const float4&h0,const float4&h1,const float4&h2v,
    const float4&w0,const float4&w1,const float4&w2,
    float&m,float&den,float4&a0,float4&a1,float4&a2){
  const ushort4* p0=(const ushort4*)(hs2+(size_t)s0i*D_OUT);
  const ushort4* p1=(const ushort4*)(hs2+(size_t)s1i*D_OUT);
  float4 u0=bf4_to_f4(p0[l]),u1=bf4_to_f4(p0[64+l]),u2=bf4_to_f4(p0[128+l]);
  float4 v0=bf4_to_f4(p1[l]),v1=bf4_to_f4(p1[64+l]),v2=bf4_to_f4(p1[128+l]);
  float s0=score12(u0,u1,u2,h0,h1,h2v,w0,w1,w2);
  float s1=score12(v0,v1,v2,h0,h1,h2v,w0,w1,w2);
  #pragma unroll
  for(int off=1; off<64; off<<=1){ s0+=__shfl_xor(s0,off,64); s1+=__shfl_xor(s1,off,64); }
  float mn=fmaxf(m,fmaxf(s0,s1));
  rescale_if(mn,m,den,a0,a1,a2);
  float q0=expf(s0-m), q1=expf(s1-m);
  den+=q0+q1;
  axpy12(q0,u0,u1,u2,a0,a1,a2);
  axpy12(q1,v0,v1,v2,a0,a1,a2);
}
__device__ __forceinline__ void f2_one(const unsigned short* __restrict__ hs2,
    int s0i, int l,
    const float4&h0,const float4&h1,const float4&h2v,
    const float4&w0,const float4&w1,const float4&w2,
    float&m,float&den,float4&a0,float4&a1,float4&a2){
  const ushort4* p0=(const ushort4*)(hs2+(size_t)s0i*D_OUT);
  float4 u0=bf4_to_f4(p0[l]),u1=bf4_to_f4(p0[64+l]),u2=bf4_to_f4(p0[128+l]);
  float s0=score12(u0,u1,u2,h0,h1,h2v,w0,w1,w2);
  #pragma unroll
  for(int off=1; off<64; off<<=1) s0+=__shfl_xor(s0,off,64);
  float mn=fmaxf(m,s0);
  rescale_if(mn,m,den,a0,a1,a2);
  float q0=expf(s0-m);
  den+=q0;
  axpy12(q0,u0,u1,u2,a0,a1,a2);
}

// ---------------- CSR build (by destination) ----------------
__global__ void k_count(const int* __restrict__ ed, int* __restrict__ deg){
  int e = blockIdx.x*256 + threadIdx.x;
  if(e < N_EDGES) atomicAdd(&deg[ed[e]], 1);
}

__global__ void k_scan(const int* __restrict__ deg, int* __restrict__ row_ptr, int* __restrict__ cursor){
  __shared__ int part[256];
  int t = threadIdx.x;
  const int CH = (N_NODES + 255) / 256;
  int base = t * CH;
  int s = 0;
  for(int i=0;i<CH;i++){ int n = base+i; if(n < N_NODES) s += deg[n]; }
  part[t] = s;
  __syncthreads();
  for(int off=1; off<256; off<<=1){
    int v = (t >= off) ? part[t-off] : 0;
    __syncthreads();
    part[t] += v;
    __syncthreads();
  }
  int run = (t==0) ? 0 : part[t-1];
  for(int i=0;i<CH;i++){
    int n = base+i;
    if(n < N_NODES){ row_ptr[n] = run; cursor[n] = run; run += deg[n]; }
  }
  if(t == 255) row_ptr[N_NODES] = run;
}

// scatter stores SOURCE id directly in CSR order (no eidx indirection downstream)
__global__ void k_scatter(const int* __restrict__ es, const int* __restrict__ ed,
                          int* __restrict__ cursor, int* __restrict__ sidx){
  int e = blockIdx.x*256 + threadIdx.x;
  if(e < N_EDGES){
    int pos = atomicAdd(&cursor[ed[e]], 1);
    sidx[pos] = es[e];
  }
}

// ---------------- Layer 1: node transforms (K=4), bf16 outputs ----------------
__global__ void k_gemm1(const float* __restrict__ feat, const float* __restrict__ Ws,
                        const float* __restrict__ Wd,
                        unsigned short* __restrict__ hs1, unsigned short* __restrict__ hd1){
  int idx = blockIdx.x*256 + threadIdx.x;
  if(idx >= N_NODES*D_H1) return;
  int n = idx >> 7, hf = idx & 127;
  float f0 = feat[n*4+0], f1 = feat[n*4+1], f2 = feat[n*4+2], f3 = feat[n*4+3];
  hs1[idx] = f2bf(f0*Ws[hf] + f1*Ws[128+hf] + f2*Ws[256+hf] + f3*Ws[384+hf]);
  hd1[idx] = f2bf(f0*Wd[hf] + f1*Wd[128+hf] + f2*Wd[256+hf] + f3*Wd[384+hf]);
}

// ---------------- Layer 1 fused: sidx-prefetch + unroll-2 ----------------
__global__ void k_fused1(const unsigned short* __restrict__ hs1, const unsigned short* __restrict__ hd1,
                         const int* __restrict__ row_ptr, const int* __restrict__ sidx,
                         const float* __restrict__ attn1,
                         unsigned short* __restrict__ h1){
  int node = blockIdx.x*4 + (threadIdx.x >> 6);
  int l = threadIdx.x & 63;
  if(node >= N_NODES) return;
  int rp = row_ptr[node], re = row_ptr[node+1];
  int deg = re - rp;                       // >=1 (self-loop)
  float hda = bf2f(hd1[(size_t)node*D_H1 + l]);
  float hdb = bf2f(hd1[(size_t)node*D_H1 + 64 + l]);
  float awa = attn1[l], awb = attn1[64 + l];
  float m0 = -INFINITY, m1 = -INFINITY;
  float d0 = 0.f, d1 = 0.f, a0 = 0.f, a1 = 0.f;

  // prefetch adjacency (deg<=64 fast path; E/N=9 so always in practice)
  int sv = sidx[rp + ((l < deg) ? l : (deg-1))];
  bool fast = (deg <= 64);

  int k = 0;
  for(; k+1 < deg; k += 2){
    int s0 = fast ? __shfl(sv, k, 64)   : sidx[rp+k];
    int s1 = fast ? __shfl(sv, k+1, 64) : sidx[rp+k+1];
    float xa0 = bf2f(hs1[(size_t)s0*D_H1 + l]);
    float xb0 = bf2f(hs1[(size_t)s0*D_H1 + 64 + l]);
    float xa1 = bf2f(hs1[(size_t)s1*D_H1 + l]);
    float xb1 = bf2f(hs1[(size_t)s1*D_H1 + 64 + l]);
    float ta0 = leaky1(xa0 + hda) * awa;
    float tb0 = leaky1(xb0 + hdb) * awb;
    float ta1 = leaky1(xa1 + hda) * awa;
    float tb1 = leaky1(xb1 + hdb) * awb;
    #pragma unroll
    for(int off=1; off<16; off<<=1){
      ta0 += __shfl_xor(ta0, off, 64);
      tb0 += __shfl_xor(tb0, off, 64);
      ta1 += __shfl_xor(ta1, off, 64);
      tb1 += __shfl_xor(tb1, off, 64);
    }
    float mn0 = fmaxf(m0, fmaxf(ta0, ta1));
    float mn1 = fmaxf(m1, fmaxf(tb0, tb1));
    float r0 = expf(m0 - mn0), r1 = expf(m1 - mn1);
    float wa0 = expf(ta0 - mn0), wa1 = expf(ta1 - mn0);
    float wb0 = expf(tb0 - mn1), wb1 = expf(tb1 - mn1);
    d0 = d0*r0 + wa0 + wa1;
    d1 = d1*r1 + wb0 + wb1;
    a0 = a0*r0 + wa0*xa0 + wa1*xa1;
    a1 = a1*r1 + wb0*xb0 + wb1*xb1;
    m0 = mn0; m1 = mn1;
  }
  if(k < deg){
    int s = fast ? __shfl(sv, k, 64) : sidx[rp+k];
    float xa = bf2f(hs1[(size_t)s*D_H1 + l]);
    float xb = bf2f(hs1[(size_t)s*D_H1 + 64 + l]);
    float t0 = leaky1(xa + hda) * awa;
    float t1 = leaky1(xb + hdb) * awb;
    #pragma unroll
    for(int off=1; off<16; off<<=1){
      t0 += __shfl_xor(t0, off, 64);
      t1 += __shfl_xor(t1, off, 64);
    }
    float mn0 = fmaxf(m0, t0), mn1 = fmaxf(m1, t1);
    float r0 = expf(m0 - mn0), r1 = expf(m1 - mn1);
    float w0 = expf(t0 - mn0), w1 = expf(t1 - mn1);
    d0 = d0*r0 + w0;      d1 = d1*r1 + w1;
    a0 = a0*r0 + w0*xa;   a1 = a1*r1 + w1*xb;
    m0 = mn0; m1 = mn1;
  }
  float v0 = a0 / d0, v1 = a1 / d1;
  v0 = v0 > 0.f ? v0 : expm1f(v0);
  v1 = v1 > 0.f ? v1 : expm1f(v1);
  h1[(size_t)node*D_H1 + l]      = f2bf(v0);
  h1[(size_t)node*D_H1 + 64 + l] = f2bf(v1);
}

// ---------------- W2 prep: fp32 [k][768] -> bf16 transposed [col][k] ----------------
__global__ void k_wprep(const float* __restrict__ Ws, const float* __restrict__ Wd,
                        unsigned short* __restrict__ WtS, unsigned short* __restrict__ WtD){
  int i = blockIdx.x*256 + threadIdx.x;   // over 768*128
  if(i >= D_OUT*D_H1) return;
  int c = i >> 7, k = i & 127;
  WtS[i] = f2bf(Ws[(size_t)k*D_OUT + c]);
  WtD[i] = f2bf(Wd[(size_t)k*D_OUT + c]);
}

// ---------------- Layer 2: MFMA bf16 GEMM (20000x128)@(128x768), both mats ----------------
__global__ __launch_bounds__(256) void k_gemm2m(const unsigned short* __restrict__ h1b,
                        const unsigned short* __restrict__ WtS, const unsigned short* __restrict__ WtD,
                        unsigned short* __restrict__ hs2, unsigned short* __restrict__ hd2){
  int wave = threadIdx.x >> 6, lane = threadIdx.x & 63;
  int wr = wave >> 1, wc = wave & 1;
  int m0 = blockIdx.x*64 + wr*32;
  int c0 = blockIdx.y*128 + wc*64;
  int lr = lane & 15, lk = lane >> 4;

  f32x4 acc[2][4][2];
  #pragma unroll
  for(int a=0;a<2;a++)
    #pragma unroll
    for(int j=0;j<4;j++)
      #pragma unroll
      for(int mmat=0;mmat<2;mmat++)
        acc[a][j][mmat] = (f32x4){0.f,0.f,0.f,0.f};

  int ra0 = m0 + lr;      if(ra0 > N_NODES-1) ra0 = N_NODES-1;
  int ra1 = m0 + 16 + lr; if(ra1 > N_NODES-1) ra1 = N_NODES-1;
  const unsigned short* pa0 = h1b + (size_t)ra0*D_H1 + lk*8;
  const unsigned short* pa1 = h1b + (size_t)ra1*D_H1 + lk*8;

  #pragma unroll
  for(int t=0;t<4;t++){              // K = 4 x 32
    bf16x8 a0 = *(const bf16x8*)(pa0 + t*32);
    bf16x8 a1 = *(const bf16x8*)(pa1 + t*32);
    #pragma unroll
    for(int j=0;j<4;j++){
      size_t bo = (size_t)(c0 + j*16 + lr)*D_H1 + t*32 + lk*8;
      bf16x8 bs = *(const bf16x8*)(WtS + bo);
      bf16x8 bd = *(const bf16x8*)(WtD + bo);
      acc[0][j][0] = __builtin_amdgcn_mfma_f32_16x16x32_bf16(a0, bs, acc[0][j][0], 0, 0, 0);
      acc[1][j][0] = __builtin_amdgcn_mfma_f32_16x16x32_bf16(a1, bs, acc[1][j][0], 0, 0, 0);
      acc[0][j][1] = __builtin_amdgcn_mfma_f32_16x16x32_bf16(a0, bd, acc[0][j][1], 0, 0, 0);
      acc[1][j][1] = __builtin_amdgcn_mfma_f32_16x16x32_bf16(a1, bd, acc[1][j][1], 0, 0, 0);
    }
  }

  #pragma unroll
  for(int a=0;a<2;a++){
    #pragma unroll
    for(int r=0;r<4;r++){
      int row = m0 + a*16 + lk*4 + r;
      if(row < N_NODES){
        size_t base = (size_t)row*D_OUT;
        #pragma unroll
        for(int j=0;j<4;j++){
          int col = c0 + j*16 + lr;
          hs2[base + col] = f2bf(acc[a][j][0][r]);
          hd2[base + col] = f2bf(acc[a][j][1][r]);
        }
      }
    }
  }
}

// ---------------- Layer 2 fused v4: 1 node/wave, unroll-2, sidx register prefetch ----------------
__global__ __launch_bounds__(256) void k_fused2(const unsigned short* __restrict__ hs2,
                         const unsigned short* __restrict__ hd2,
                         const int* __restrict__ row_ptr, const int* __restrict__ sidx,
                         const float* __restrict__ attn2,
                         unsigned short* __restrict__ h2){
  int node = blockIdx.x*4 + (threadIdx.x >> 6);
  int l = threadIdx.x & 63;
  if(node >= N_NODES) return;
  int rp = row_ptr[node], re = row_ptr[node+1];
  int deg = re - rp;                       // >=1 (self-loop)

  const float4* pa = (const float4*)attn2;
  float4 aw0 = pa[l], aw1 = pa[64+l], aw2 = pa[128+l];
  const ushort4* pd = (const ushort4*)(hd2 + (size_t)node*D_OUT);
  float4 hd0 = bf4_to_f4(pd[l]), hd1v = bf4_to_f4(pd[64+l]), hd2v = bf4_to_f4(pd[128+l]);

  // prefetch adjacency into one register (deg<=64 fast path)
  int sv = sidx[rp + ((l < deg) ? l : (deg-1))];
  bool fast = (deg <= 64);

  float m = -INFINITY, den = 0.f;
  float4 ac0 = make_float4(0,0,0,0), ac1 = ac0, ac2 = ac0;

  int k = 0;
  for(; k+1 < deg; k += 2){
    int s0 = fast ? __shfl(sv, k, 64)   : sidx[rp+k];
    int s1 = fast ? __shfl(sv, k+1, 64) : sidx[rp+k+1];
    f2_pair(hs2, s0, s1, l, hd0, hd1v, hd2v, aw0, aw1, aw2, m, den, ac0, ac1, ac2);
  }
  if(k < deg){
    int s0 = fast ? __shfl(sv, k, 64) : sidx[rp+k];
    f2_one(hs2, s0, l, hd0, hd1v, hd2v, aw0, aw1, aw2, m, den, ac0, ac1, ac2);
  }

  float rd = 1.f/den;
  ushort4* po = (ushort4*)(h2 + (size_t)node*D_OUT);
  ac0.x*=rd; ac0.y*=rd; ac0.z*=rd; ac0.w*=rd;
  ac1.x*=rd; ac1.y*=rd; ac1.z*=rd; ac1.w*=rd;
  ac2.x*=rd; ac2.y*=rd; ac2.z*=rd; ac2.w*=rd;
  po[l] = f4_to_bf4(ac0); po[64+l] = f4_to_bf4(ac1); po[128+l] = f4_to_bf4(ac2);
}

// ---------------- Output assembly (h2 bf16) ----------------
__global__ __launch_bounds__(192) void k_out(const unsigned short* __restrict__ h2,
    const int* __restrict__ tok, const int* __restrict__ mins, const int* __restrict__ wkd,
    const int* __restrict__ dayl, const int* __restrict__ grd,
    const float* __restrict__ grid_t, const float* __restrict__ dayt_t,
    const float* __restrict__ week_t, const float* __restrict__ day_t,
    float* __restrict__ out){
  int bs = blockIdx.x;
  int t  = threadIdx.x;
  int s  = bs & (S_LEN-1);
  int tk = tok[bs], mn = mins[bs], wk = wkd[bs], dy = dayl[bs], gr = grd[bs];
  float4 r = bf4_to_f4(((const ushort4*)(h2 + (size_t)tk*D_OUT))[t]);
  float4 v;
  v = ((const float4*)(week_t + (size_t)wk*D_OUT))[t]; r.x+=v.x; r.y+=v.y; r.z+=v.z; r.w+=v.w;
  v = ((const float4*)(dayt_t + (size_t)mn*D_OUT))[t]; r.x+=v.x; r.y+=v.y; r.z+=v.z; r.w+=v.w;
  v = ((const float4*)(day_t  + (size_t)dy*D_OUT))[t]; r.x+=v.x; r.y+=v.y; r.z+=v.z; r.w+=v.w;
  v = ((const float4*)(grid_t + (size_t)gr*D_OUT))[t]; r.x+=v.x; r.y+=v.y; r.z+=v.z; r.w+=v.w;
  const float K = 0.011992630692677313f;   // ln(10000)/768
  float d0 = expf(-K * (float)(4*t));
  float d1 = expf(-K * (float)(4*t+2));
  float sf = (float)s;
  r.x += sinf(sf*d0); r.y += cosf(sf*d0);
  r.z += sinf(sf*d1); r.w += cosf(sf*d1);
  ((float4*)(out + (size_t)bs*D_OUT))[t] = r;
}

extern "C" void kernel_launch(void* const* d_in, const int* in_sizes, int n_in,
                              void* d_out, int out_size, void* d_ws, size_t ws_size,
                              hipStream_t stream) {
  const int*   trj   = (const int*)  d_in[0];
  const int*   mins  = (const int*)  d_in[1];
  const int*   wkd   = (const int*)  d_in[2];
  const int*   dayl  = (const int*)  d_in[3];
  const int*   grd   = (const int*)  d_in[4];
  const int*   es    = (const int*)  d_in[6];
  const int*   ed    = (const int*)  d_in[7];
  const float* feat  = (const float*)d_in[8];
  const float* Ws1   = (const float*)d_in[9];
  const float* Wd1   = (const float*)d_in[10];
  const float* attn1 = (const float*)d_in[11];
  const float* Ws2   = (const float*)d_in[12];
  const float* Wd2   = (const float*)d_in[13];
  const float* attn2 = (const float*)d_in[14];
  const float* gridt = (const float*)d_in[15];
  const float* daytt = (const float*)d_in[16];
  const float* weekt = (const float*)d_in[17];
  const float* dayt  = (const float*)d_in[18];
  float* out = (float*)d_out;

  char* ws = (char*)d_ws;
  size_t off = 0;
  auto alloc = [&](size_t bytes)->char*{
    char* p = ws + off;
    off += bytes;
    off = (off + 255) & ~(size_t)255;
    return p;
  };
  unsigned short* hs1 = (unsigned short*)alloc((size_t)N_NODES*D_H1*2);
  unsigned short* hd1 = (unsigned short*)alloc((size_t)N_NODES*D_H1*2);
  unsigned short* h1  = (unsigned short*)alloc((size_t)N_NODES*D_H1*2);
  unsigned short* WtS = (unsigned short*)alloc((size_t)D_OUT*D_H1*2);
  unsigned short* WtD = (unsigned short*)alloc((size_t)D_OUT*D_H1*2);
  unsigned short* hs2 = (unsigned short*)alloc((size_t)N_NODES*D_OUT*2);
  unsigned short* hd2 = (unsigned short*)alloc((size_t)N_NODES*D_OUT*2);
  unsigned short* h2  = (unsigned short*)alloc((size_t)N_NODES*D_OUT*2);
  int* deg      = (int*)alloc((size_t)N_NODES*4);
  int* row_ptr  = (int*)alloc((size_t)(N_NODES+1)*4);
  int* cursor   = (int*)alloc((size_t)N_NODES*4);
  int* sidx     = (int*)alloc((size_t)N_EDGES*4);

  // CSR by destination (ws re-poisoned each run -> must zero deg)
  hipMemsetAsync(deg, 0, (size_t)N_NODES*4, stream);
  k_count  <<<(N_EDGES+255)/256, 256, 0, stream>>>(ed, deg);
  k_scan   <<<1, 256, 0, stream>>>(deg, row_ptr, cursor);
  k_scatter<<<(N_EDGES+255)/256, 256, 0, stream>>>(es, ed, cursor, sidx);

  // Layer 1
  k_gemm1 <<<(N_NODES*D_H1)/256, 256, 0, stream>>>(feat, Ws1, Wd1, hs1, hd1);
  k_fused1<<<(N_NODES+3)/4, 256, 0, stream>>>(hs1, hd1, row_ptr, sidx, attn1, h1);

  // Layer 2 (MFMA)
  k_wprep <<<(D_OUT*D_H1+255)/256, 256, 0, stream>>>(Ws2, Wd2, WtS, WtD);
  dim3 g2((N_NODES+63)/64, D_OUT/128);
  k_gemm2m<<<g2, 256, 0, stream>>>(h1, WtS, WtD, hs2, hd2);
  k_fused2<<<(N_NODES+3)/4, 256, 0, stream>>>(hs2, hd2, row_ptr, sidx, attn2, h2);

  // Output
  k_out<<<B_SZ*S_LEN, 192, 0, stream>>>(h2, trj, mins, wkd, dayl, grd,
                                        gridt, daytt, weekt, dayt, out);
}

// Round 15
// 338.959 us; speedup vs baseline: 1.0727x; 1.0007x over previous
//
#include <hip/hip_runtime.h>
#include <hip/hip_bf16.h>

#define N_NODES 20000
#define N_EDGES 180000
#define D_OUT   768
#define D_H1    128
#define B_SZ    16
#define S_LEN   512
#define NEG_SLOPE_C 0.2f

typedef __attribute__((ext_vector_type(8))) short bf16x8;   // 8 bf16 = 4 VGPRs
typedef __attribute__((ext_vector_type(4))) float f32x4;    // MFMA acc

__device__ __forceinline__ float leaky1(float x){ return x >= 0.0f ? x : NEG_SLOPE_C * x; }
__device__ __forceinline__ unsigned short f2bf(float x){
  union { __hip_bfloat16 h; unsigned short u; } v; v.h = __float2bfloat16(x); return v.u;
}
__device__ __forceinline__ float bf2f(unsigned short u){
  return __uint_as_float(((unsigned)u) << 16);
}
__device__ __forceinline__ float4 bf4_to_f4(ushort4 u){
  return make_float4(bf2f(u.x), bf2f(u.y), bf2f(u.z), bf2f(u.w));
}
__device__ __forceinline__ ushort4 f4_to_bf4(float4 v){
  ushort4 u; u.x=f2bf(v.x); u.y=f2bf(v.y); u.z=f2bf(v.z); u.w=f2bf(v.w); return u;
}

// 12-element leaky-dot for layer-2 scores
__device__ __forceinline__ float score12(const float4&u0,const float4&u1,const float4&u2,
                                         const float4&h0,const float4&h1,const float4&h2v,
                                         const float4&a0,const float4&a1,const float4&a2){
  return leaky1(u0.x+h0.x)*a0.x + leaky1(u0.y+h0.y)*a0.y
       + leaky1(u0.z+h0.z)*a0.z + leaky1(u0.w+h0.w)*a0.w
       + leaky1(u1.x+h1.x)*a1.x + leaky1(u1.y+h1.y)*a1.y
       + leaky1(u1.z+h1.z)*a1.z + leaky1(u1.w+h1.w)*a1.w
       + leaky1(u2.x+h2v.x)*a2.x + leaky1(u2.y+h2v.y)*a2.y
       + leaky1(u2.z+h2v.z)*a2.z + leaky1(u2.w+h2v.w)*a2.w;
}
__device__ __forceinline__ void rescale_if(float mn, float&m, float&den,
                                           float4&a0,float4&a1,float4&a2){
  if(mn > m){                               // wave-uniform (scores reduced over wave)
    float r = expf(m - mn);                 // first time: expf(-inf)=0
    den *= r;
    a0.x*=r; a0.y*=r; a0.z*=r; a0.w*=r;
    a1.x*=r; a1.y*=r; a1.z*=r; a1.w*=r;
    a2.x*=r; a2.y*=r; a2.z*=r; a2.w*=r;
    m = mn;
  }
}
__device__ __forceinline__ void axpy12(float w, const float4&u0,const float4&u1,const float4&u2,
                                       float4&a0,float4&a1,float4&a2){
  a0.x+=w*u0.x; a0.y+=w*u0.y; a0.z+=w*u0.z; a0.w+=w*u0.w;
  a1.x+=w*u1.x; a1.y+=w*u1.y; a1.z+=w*u1.z; a1.w+=w*u1.w;
  a2.x+=w*u2.x; a2.y+=w*u2.y; a2.z+=w*u2.z; a2.w+=w*u2.w;
}
// fused2 bodies: src ids passed directly (no index loads inside)
__device__ __forceinline__ void f2_pair(const unsigned short* __restrict__ hs2,
    int s0i, int s1i, int l,
    const float4&h0,const float4&h1,const float4&h2v,
    const float4&w0,const float4&w1,const float4&w2,
    float&m,float&den,float4&a0,float4&a1,float4&a2){
  const ushort4* p0=(const ushort4*)(hs2+(size_t)s0i*D_OUT);
  const ushort4* p1=(const ushort4*)(hs2+(size_t)s1i*D_OUT);
  float4 u0=bf4_to_f4(p0[l]),u1=bf4_to_f4(p0[64+l]),u2=bf4_to_f4(p0[128+l]);
  float4 v0=bf4_to_f4(p1[l]),v1=bf4_to_f4(p1[64+l]),v2=bf4_to_f4(p1[128+l]);
  float s0=score12(u0,u1,u2,h0,h1,h2v,w0,w1,w2);
  float s1=score12(v0,v1,v2,h0,h1,h2v,w0,w1,w2);
  #pragma unroll
  for(int off=1; off<64; off<<=1){ s0+=__shfl_xor(s0,off,64); s1+=__shfl_xor(s1,off,64); }
  float mn=fmaxf(m,fmaxf(s0,s1));
  rescale_if(mn,m,den,a0,a1,a2);
  float q0=expf(s0-m), q1=expf(s1-m);
  den+=q0+q1;
  axpy12(q0,u0,u1,u2,a0,a1,a2);
  axpy12(q1,v0,v1,v2,a0,a1,a2);
}
__device__ __forceinline__ void f2_one(const unsigned short* __restrict__ hs2,
    int s0i, int l,
    const float4&h0,const float4&h1,const float4&h2v,
    const float4&w0,const float4&w1,const float4&w2,
    float&m,float&den,float4&a0,float4&a1,float4&a2){
  const ushort4* p0=(const ushort4*)(hs2+(size_t)s0i*D_OUT);
  float4 u0=bf4_to_f4(p0[l]),u1=bf4_to_f4(p0[64+l]),u2=bf4_to_f4(p0[128+l]);
  float s0=score12(u0,u1,u2,h0,h1,h2v,w0,w1,w2);
  #pragma unroll
  for(int off=1; off<64; off<<=1) s0+=__shfl_xor(s0,off,64);
  float mn=fmaxf(m,s0);
  rescale_if(mn,m,den,a0,a1,a2);
  float q0=expf(s0-m);
  den+=q0;
  axpy12(q0,u0,u1,u2,a0,a1,a2);
}

// ---------------- CSR build (by destination) ----------------
__global__ void k_count(const int* __restrict__ ed, int* __restrict__ deg){
  int e = blockIdx.x*256 + threadIdx.x;
  if(e < N_EDGES) atomicAdd(&deg[ed[e]], 1);
}

__global__ void k_scan(const int* __restrict__ deg, int* __restrict__ row_ptr, int* __restrict__ cursor){
  __shared__ int part[256];
  int t = threadIdx.x;
  const int CH = (N_NODES + 255) / 256;
  int base = t * CH;
  int s = 0;
  for(int i=0;i<CH;i++){ int n = base+i; if(n < N_NODES) s += deg[n]; }
  part[t] = s;
  __syncthreads();
  for(int off=1; off<256; off<<=1){
    int v = (t >= off) ? part[t-off] : 0;
    __syncthreads();
    part[t] += v;
    __syncthreads();
  }
  int run = (t==0) ? 0 : part[t-1];
  for(int i=0;i<CH;i++){
    int n = base+i;
    if(n < N_NODES){ row_ptr[n] = run; cursor[n] = run; run += deg[n]; }
  }
  if(t == 255) row_ptr[N_NODES] = run;
}

// scatter stores SOURCE id directly in CSR order
__global__ void k_scatter(const int* __restrict__ es, const int* __restrict__ ed,
                          int* __restrict__ cursor, int* __restrict__ sidx){
  int e = blockIdx.x*256 + threadIdx.x;
  if(e < N_EDGES){
    int pos = atomicAdd(&cursor[ed[e]], 1);
    sidx[pos] = es[e];
  }
}

// ---------------- Layer 1 fused v3: feat-gather (16B/edge) + on-the-fly transform ----------------
// hs1[s][l] = dot4(feat[s], Ws1[:,l]) recomputed per edge; Ws1/Wd1 columns in registers.
// No hs1/hd1 buffers, no k_gemm1.
__global__ void k_fused1(const float* __restrict__ feat,
                         const float* __restrict__ Ws1, const float* __restrict__ Wd1,
                         const int* __restrict__ row_ptr, const int* __restrict__ sidx,
                         const float* __restrict__ attn1,
                         unsigned short* __restrict__ h1){
  int node = blockIdx.x*4 + (threadIdx.x >> 6);
  int l = threadIdx.x & 63;
  if(node >= N_NODES) return;
  int rp = row_ptr[node], re = row_ptr[node+1];
  int deg = re - rp;                       // >=1 (self-loop)

  // per-lane weight columns: element l and 64+l of each k-row
  float wsA[4], wsB[4], wdA[4], wdB[4];
  #pragma unroll
  for(int k2=0;k2<4;k2++){
    wsA[k2] = Ws1[k2*D_H1 + l];      wsB[k2] = Ws1[k2*D_H1 + 64 + l];
    wdA[k2] = Wd1[k2*D_H1 + l];      wdB[k2] = Wd1[k2*D_H1 + 64 + l];
  }
  float4 fn = *(const float4*)(feat + (size_t)node*4);
  float hda = fn.x*wdA[0] + fn.y*wdA[1] + fn.z*wdA[2] + fn.w*wdA[3];
  float hdb = fn.x*wdB[0] + fn.y*wdB[1] + fn.z*wdB[2] + fn.w*wdB[3];
  float awa = attn1[l], awb = attn1[64 + l];

  // prefetch adjacency into one register (deg<=64 fast path)
  int sv = sidx[rp + ((l < deg) ? l : (deg-1))];
  bool fast = (deg <= 64);

  float m0 = -INFINITY, m1 = -INFINITY;
  float d0 = 0.f, d1 = 0.f, a0 = 0.f, a1 = 0.f;
  int k = 0;
  for(; k+1 < deg; k += 2){
    int s0 = fast ? __shfl(sv, k, 64)   : sidx[rp+k];
    int s1 = fast ? __shfl(sv, k+1, 64) : sidx[rp+k+1];
    float4 f0v = *(const float4*)(feat + (size_t)s0*4);   // wave-uniform broadcast
    float4 f1v = *(const float4*)(feat + (size_t)s1*4);
    float xa0 = f0v.x*wsA[0] + f0v.y*wsA[1] + f0v.z*wsA[2] + f0v.w*wsA[3];
    float xb0 = f0v.x*wsB[0] + f0v.y*wsB[1] + f0v.z*wsB[2] + f0v.w*wsB[3];
    float xa1 = f1v.x*wsA[0] + f1v.y*wsA[1] + f1v.z*wsA[2] + f1v.w*wsA[3];
    float xb1 = f1v.x*wsB[0] + f1v.y*wsB[1] + f1v.z*wsB[2] + f1v.w*wsB[3];
    float ta0 = leaky1(xa0 + hda) * awa;
    float tb0 = leaky1(xb0 + hdb) * awb;
    float ta1 = leaky1(xa1 + hda) * awa;
    float tb1 = leaky1(xb1 + hdb) * awb;
    #pragma unroll
    for(int off=1; off<16; off<<=1){
      ta0 += __shfl_xor(ta0, off, 64);
      tb0 += __shfl_xor(tb0, off, 64);
      ta1 += __shfl_xor(ta1, off, 64);
      tb1 += __shfl_xor(tb1, off, 64);
    }
    float mn0 = fmaxf(m0, fmaxf(ta0, ta1));
    float mn1 = fmaxf(m1, fmaxf(tb0, tb1));
    float r0 = expf(m0 - mn0), r1 = expf(m1 - mn1);   // first iter: expf(-inf)=0
    float wa0 = expf(ta0 - mn0), wa1 = expf(ta1 - mn0);
    float wb0 = expf(tb0 - mn1), wb1 = expf(tb1 - mn1);
    d0 = d0*r0 + wa0 + wa1;
    d1 = d1*r1 + wb0 + wb1;
    a0 = a0*r0 + wa0*xa0 + wa1*xa1;
    a1 = a1*r1 + wb0*xb0 + wb1*xb1;
    m0 = mn0; m1 = mn1;
  }
  if(k < deg){
    int s = fast ? __shfl(sv, k, 64) : sidx[rp+k];
    float4 fv = *(const float4*)(feat + (size_t)s*4);
    float xa = fv.x*wsA[0] + fv.y*wsA[1] + fv.z*wsA[2] + fv.w*wsA[3];
    float xb = fv.x*wsB[0] + fv.y*wsB[1] + fv.z*wsB[2] + fv.w*wsB[3];
    float t0 = leaky1(xa + hda) * awa;
    float t1 = leaky1(xb + hdb) * awb;
    #pragma unroll
    for(int off=1; off<16; off<<=1){
      t0 += __shfl_xor(t0, off, 64);
      t1 += __shfl_xor(t1, off, 64);
    }
    float mn0 = fmaxf(m0, t0), mn1 = fmaxf(m1, t1);
    float r0 = expf(m0 - mn0), r1 = expf(m1 - mn1);
    float w0 = expf(t0 - mn0), w1 = expf(t1 - mn1);
    d0 = d0*r0 + w0;      d1 = d1*r1 + w1;
    a0 = a0*r0 + w0*xa;   a1 = a1*r1 + w1*xb;
    m0 = mn0; m1 = mn1;
  }
  float v0 = a0 / d0, v1 = a1 / d1;
  v0 = v0 > 0.f ? v0 : expm1f(v0);
  v1 = v1 > 0.f ? v1 : expm1f(v1);
  h1[(size_t)node*D_H1 + l]      = f2bf(v0);
  h1[(size_t)node*D_H1 + 64 + l] = f2bf(v1);
}

// ---------------- W2 prep: fp32 [k][768] -> bf16 transposed [col][k] ----------------
__global__ void k_wprep(const float* __restrict__ Ws, const float* __restrict__ Wd,
                        unsigned short* __restrict__ WtS, unsigned short* __restrict__ WtD){
  int i = blockIdx.x*256 + threadIdx.x;   // over 768*128
  if(i >= D_OUT*D_H1) return;
  int c = i >> 7, k = i & 127;
  WtS[i] = f2bf(Ws[(size_t)k*D_OUT + c]);
  WtD[i] = f2bf(Wd[(size_t)k*D_OUT + c]);
}

// ---------------- Layer 2: MFMA bf16 GEMM (20000x128)@(128x768), both mats ----------------
__global__ __launch_bounds__(256) void k_gemm2m(const unsigned short* __restrict__ h1b,
                        const unsigned short* __restrict__ WtS, const unsigned short* __restrict__ WtD,
                        unsigned short* __restrict__ hs2, unsigned short* __restrict__ hd2){
  int wave = threadIdx.x >> 6, lane = threadIdx.x & 63;
  int wr = wave >> 1, wc = wave & 1;
  int m0 = blockIdx.x*64 + wr*32;
  int c0 = blockIdx.y*128 + wc*64;
  int lr = lane & 15, lk = lane >> 4;

  f32x4 acc[2][4][2];
  #pragma unroll
  for(int a=0;a<2;a++)
    #pragma unroll
    for(int j=0;j<4;j++)
      #pragma unroll
      for(int mmat=0;mmat<2;mmat++)
        acc[a][j][mmat] = (f32x4){0.f,0.f,0.f,0.f};

  int ra0 = m0 + lr;      if(ra0 > N_NODES-1) ra0 = N_NODES-1;
  int ra1 = m0 + 16 + lr; if(ra1 > N_NODES-1) ra1 = N_NODES-1;
  const unsigned short* pa0 = h1b + (size_t)ra0*D_H1 + lk*8;
  const unsigned short* pa1 = h1b + (size_t)ra1*D_H1 + lk*8;

  #pragma unroll
  for(int t=0;t<4;t++){              // K = 4 x 32
    bf16x8 a0 = *(const bf16x8*)(pa0 + t*32);
    bf16x8 a1 = *(const bf16x8*)(pa1 + t*32);
    #pragma unroll
    for(int j=0;j<4;j++){
      size_t bo = (size_t)(c0 + j*16 + lr)*D_H1 + t*32 + lk*8;
      bf16x8 bs = *(const bf16x8*)(WtS + bo);
      bf16x8 bd = *(const bf16x8*)(WtD + bo);
      acc[0][j][0] = __builtin_amdgcn_mfma_f32_16x16x32_bf16(a0, bs, acc[0][j][0], 0, 0, 0);
      acc[1][j][0] = __builtin_amdgcn_mfma_f32_16x16x32_bf16(a1, bs, acc[1][j][0], 0, 0, 0);
      acc[0][j][1] = __builtin_amdgcn_mfma_f32_16x16x32_bf16(a0, bd, acc[0][j][1], 0, 0, 0);
      acc[1][j][1] = __builtin_amdgcn_mfma_f32_16x16x32_bf16(a1, bd, acc[1][j][1], 0, 0, 0);
    }
  }

  #pragma unroll
  for(int a=0;a<2;a++){
    #pragma unroll
    for(int r=0;r<4;r++){
      int row = m0 + a*16 + lk*4 + r;
      if(row < N_NODES){
        size_t base = (size_t)row*D_OUT;
        #pragma unroll
        for(int j=0;j<4;j++){
          int col = c0 + j*16 + lr;
          hs2[base + col] = f2bf(acc[a][j][0][r]);
          hd2[base + col] = f2bf(acc[a][j][1][r]);
        }
      }
    }
  }
}

// ---------------- Layer 2 fused v4: 1 node/wave, unroll-2, sidx register prefetch ----------------
__global__ __launch_bounds__(256) void k_fused2(const unsigned short* __restrict__ hs2,
                         const unsigned short* __restrict__ hd2,
                         const int* __restrict__ row_ptr, const int* __restrict__ sidx,
                         const float* __restrict__ attn2,
                         unsigned short* __restrict__ h2){
  int node = blockIdx.x*4 + (threadIdx.x >> 6);
  int l = threadIdx.x & 63;
  if(node >= N_NODES) return;
  int rp = row_ptr[node], re = row_ptr[node+1];
  int deg = re - rp;                       // >=1 (self-loop)

  const float4* pa = (const float4*)attn2;
  float4 aw0 = pa[l], aw1 = pa[64+l], aw2 = pa[128+l];
  const ushort4* pd = (const ushort4*)(hd2 + (size_t)node*D_OUT);
  float4 hd0 = bf4_to_f4(pd[l]), hd1v = bf4_to_f4(pd[64+l]), hd2v = bf4_to_f4(pd[128+l]);

  int sv = sidx[rp + ((l < deg) ? l : (deg-1))];
  bool fast = (deg <= 64);

  float m = -INFINITY, den = 0.f;
  float4 ac0 = make_float4(0,0,0,0), ac1 = ac0, ac2 = ac0;

  int k = 0;
  for(; k+1 < deg; k += 2){
    int s0 = fast ? __shfl(sv, k, 64)   : sidx[rp+k];
    int s1 = fast ? __shfl(sv, k+1, 64) : sidx[rp+k+1];
    f2_pair(hs2, s0, s1, l, hd0, hd1v, hd2v, aw0, aw1, aw2, m, den, ac0, ac1, ac2);
  }
  if(k < deg){
    int s0 = fast ? __shfl(sv, k, 64) : sidx[rp+k];
    f2_one(hs2, s0, l, hd0, hd1v, hd2v, aw0, aw1, aw2, m, den, ac0, ac1, ac2);
  }

  float rd = 1.f/den;
  ushort4* po = (ushort4*)(h2 + (size_t)node*D_OUT);
  ac0.x*=rd; ac0.y*=rd; ac0.z*=rd; ac0.w*=rd;
  ac1.x*=rd; ac1.y*=rd; ac1.z*=rd; ac1.w*=rd;
  ac2.x*=rd; ac2.y*=rd; ac2.z*=rd; ac2.w*=rd;
  po[l] = f4_to_bf4(ac0); po[64+l] = f4_to_bf4(ac1); po[128+l] = f4_to_bf4(ac2);
}

// ---------------- Output assembly (h2 bf16) ----------------
__global__ __launch_bounds__(192) void k_out(const unsigned short* __restrict__ h2,
    const int* __restrict__ tok, const int* __restrict__ mins, const int* __restrict__ wkd,
    const int* __restrict__ dayl, const int* __restrict__ grd,
    const float* __restrict__ grid_t, const float* __restrict__ dayt_t,
    const float* __restrict__ week_t, const float* __restrict__ day_t,
    float* __restrict__ out){
  int bs = blockIdx.x;
  int t  = threadIdx.x;
  int s  = bs & (S_LEN-1);
  int tk = tok[bs], mn = mins[bs], wk = wkd[bs], dy = dayl[bs], gr = grd[bs];
  float4 r = bf4_to_f4(((const ushort4*)(h2 + (size_t)tk*D_OUT))[t]);
  float4 v;
  v = ((const float4*)(week_t + (size_t)wk*D_OUT))[t]; r.x+=v.x; r.y+=v.y; r.z+=v.z; r.w+=v.w;
  v = ((const float4*)(dayt_t + (size_t)mn*D_OUT))[t]; r.x+=v.x; r.y+=v.y; r.z+=v.z; r.w+=v.w;
  v = ((const float4*)(day_t  + (size_t)dy*D_OUT))[t]; r.x+=v.x; r.y+=v.y; r.z+=v.z; r.w+=v.w;
  v = ((const float4*)(grid_t + (size_t)gr*D_OUT))[t]; r.x+=v.x; r.y+=v.y; r.z+=v.z; r.w+=v.w;
  const float K = 0.011992630692677313f;   // ln(10000)/768
  float d0 = expf(-K * (float)(4*t));
  float d1 = expf(-K * (float)(4*t+2));
  float sf = (float)s;
  r.x += sinf(sf*d0); r.y += cosf(sf*d0);
  r.z += sinf(sf*d1); r.w += cosf(sf*d1);
  ((float4*)(out + (size_t)bs*D_OUT))[t] = r;
}

extern "C" void kernel_launch(void* const* d_in, const int* in_sizes, int n_in,
                              void* d_out, int out_size, void* d_ws, size_t ws_size,
                              hipStream_t stream) {
  const int*   trj   = (const int*)  d_in[0];
  const int*   mins  = (const int*)  d_in[1];
  const int*   wkd   = (const int*)  d_in[2];
  const int*   dayl  = (const int*)  d_in[3];
  const int*   grd   = (const int*)  d_in[4];
  const int*   es    = (const int*)  d_in[6];
  const int*   ed    = (const int*)  d_in[7];
  const float* feat  = (const float*)d_in[8];
  const float* Ws1   = (const float*)d_in[9];
  const float* Wd1   = (const float*)d_in[10];
  const float* attn1 = (const float*)d_in[11];
  const float* Ws2   = (const float*)d_in[12];
  const float* Wd2   = (const float*)d_in[13];
  const float* attn2 = (const float*)d_in[14];
  const float* gridt = (const float*)d_in[15];
  const float* daytt = (const float*)d_in[16];
  const float* weekt = (const float*)d_in[17];
  const float* dayt  = (const float*)d_in[18];
  float* out = (float*)d_out;

  char* ws = (char*)d_ws;
  size_t off = 0;
  auto alloc = [&](size_t bytes)->char*{
    char* p = ws + off;
    off += bytes;
    off = (off + 255) & ~(size_t)255;
    return p;
  };
  unsigned short* h1  = (unsigned short*)alloc((size_t)N_NODES*D_H1*2);
  unsigned short* WtS = (unsigned short*)alloc((size_t)D_OUT*D_H1*2);
  unsigned short* WtD = (unsigned short*)alloc((size_t)D_OUT*D_H1*2);
  unsigned short* hs2 = (unsigned short*)alloc((size_t)N_NODES*D_OUT*2);
  unsigned short* hd2 = (unsigned short*)alloc((size_t)N_NODES*D_OUT*2);
  unsigned short* h2  = (unsigned short*)alloc((size_t)N_NODES*D_OUT*2);
  int* deg      = (int*)alloc((size_t)N_NODES*4);
  int* row_ptr  = (int*)alloc((size_t)(N_NODES+1)*4);
  int* cursor   = (int*)alloc((size_t)N_NODES*4);
  int* sidx     = (int*)alloc((size_t)N_EDGES*4);

  // CSR by destination (ws re-poisoned each run -> must zero deg)
  hipMemsetAsync(deg, 0, (size_t)N_NODES*4, stream);
  k_count  <<<(N_EDGES+255)/256, 256, 0, stream>>>(ed, deg);
  k_scan   <<<1, 256, 0, stream>>>(deg, row_ptr, cursor);
  k_scatter<<<(N_EDGES+255)/256, 256, 0, stream>>>(es, ed, cursor, sidx);

  // Layer 1 (fused transform+attention; no gemm1, no hs1/hd1 buffers)
  k_fused1<<<(N_NODES+3)/4, 256, 0, stream>>>(feat, Ws1, Wd1, row_ptr, sidx, attn1, h1);

  // Layer 2 (MFMA)
  k_wprep <<<(D_OUT*D_H1+255)/256, 256, 0, stream>>>(Ws2, Wd2, WtS, WtD);
  dim3 g2((N_NODES+63)/64, D_OUT/128);
  k_gemm2m<<<g2, 256, 0, stream>>>(h1, WtS, WtD, hs2, hd2);
  k_fused2<<<(N_NODES+3)/4, 256, 0, stream>>>(hs2, hd2, row_ptr, sidx, attn2, h2);

  // Output
  k_out<<<B_SZ*S_LEN, 192, 0, stream>>>(h2, trj, mins, wkd, dayl, grd,
                                        gridt, daytt, weekt, dayt, out);
}